// Round 1
// 117519.080 us; speedup vs baseline: 1.4595x; 1.4595x over previous
//
#include <hip/hip_runtime.h>

// RNNDetector: 2-layer LSTM (H=64), T=262144 sequential steps + 16-wide head.
// ROUND 11: kill per-step synchronization. R10 measured ~1570 cyc/step vs a
// ~380 cyc VALU issue floor (VALUBusy ~35% on the active CU). The gap is
// structural: 2 barriers/step, wave1<->wave2 exb handoff on the h1 chain,
// LDS write->barrier->read turnaround, per-step global y load.
// New structure: 3 waves, block-pipelined with B=32 steps per superstep and
// ONE barrier per superstep (8195 barriers total vs 524K):
//   w0: L0 recurrence, 4 gates/lane in-lane (self-dep via own LDS ring slot,
//       no barrier needed: DS ops are in-order within a wave).
//   w1: xp1(t) = Wih1*h0(t) + b for block k-1 (no serial dep) + head out(t)
//       for block k-3.
//   w2: L1 recurrence: gates = xp1(t) + Whh1*h1(t-1), 4 gates/lane in-lane
//       (exb handoff eliminated), self-dep via own h1 ring slot.
// Ring buffers are 2 blocks (64 slots); adjacent blocks occupy disjoint
// halves, so all cross-wave same-address reuse is >= 1 barrier apart.
// y: one lane-distributed load per block (prefetched a block ahead) +
// v_readlane per step. Weight regs stay u4 ext_vector (R10 compile fix).

constexpr int T  = 262144;
constexpr int B  = 32;          // steps per superstep
constexpr int NB = T / B;       // 8192 blocks
constexpr int RS = 2 * B;       // 64 ring slots (2 blocks)
constexpr int K_SS = NB + 3;    // supersteps incl. pipeline drain

typedef _Float16 h2v __attribute__((ext_vector_type(2)));
typedef unsigned u4 __attribute__((ext_vector_type(4)));

__device__ __forceinline__ float rcp_f(float x) { return __builtin_amdgcn_rcpf(x); }

#define BARRIER() asm volatile("s_waitcnt lgkmcnt(0)\n\ts_barrier" ::: "memory")

// packed-f16 dot2: acc += w.lo*h.lo + w.hi*h.hi (f32 accumulate)
static __device__ __forceinline__ float fd(unsigned w, unsigned h, float acc) {
#if __has_builtin(__builtin_amdgcn_fdot2)
  return __builtin_amdgcn_fdot2(__builtin_bit_cast(h2v, w),
                                __builtin_bit_cast(h2v, h), acc, false);
#else
  h2v a = __builtin_bit_cast(h2v, w), b = __builtin_bit_cast(h2v, h);
  acc = fmaf((float)a.x, (float)b.x, acc);
  acc = fmaf((float)a.y, (float)b.y, acc);
  return acc;
#endif
}

#define DP4(acc, W, H) { acc = fd((W).x, (H).x, acc); acc = fd((W).y, (H).y, acc); \
                         acc = fd((W).z, (H).z, acc); acc = fd((W).w, (H).w, acc); }

// quad_perm DPP cross-lane (pure VALU, no LDS): xor1 = 0xB1, xor2 = 0x4E
#define DPPX1(x) __builtin_bit_cast(float, __builtin_amdgcn_mov_dpp(            \
                    __builtin_bit_cast(int, (x)), 0xB1, 0xF, 0xF, true))
#define DPPX2(x) __builtin_bit_cast(float, __builtin_amdgcn_mov_dpp(            \
                    __builtin_bit_cast(int, (x)), 0x4E, 0xF, 0xF, true))

__device__ __forceinline__ float sigf(float x) {
  float z = fminf(fmaxf(x, -30.f), 30.f);
  return rcp_f(1.f + __expf(-z));
}
__device__ __forceinline__ float tanhf_(float x) {
  float z = fminf(fmaxf(x, -15.f), 15.f);
  float e2 = __expf(-2.f * z);
  return (1.f - e2) * rcp_f(1.f + e2);
}

// f32 -> f16 RNE (weights |w| < ~0.7: no overflow; flush sub-6e-5 to 0)
__device__ unsigned f16rne(float f) {
  unsigned u = __float_as_uint(f);
  unsigned s = (u >> 16) & 0x8000u;
  int e = (int)((u >> 23) & 0xff) - 127;
  unsigned m = u & 0x7fffffu;
  if (e < -14) return s;
  unsigned h = s | (unsigned)((e + 15) << 10) | (m >> 13);
  unsigned rem = m & 0x1fffu;
  h += (rem > 0x1000u) || (rem == 0x1000u && (h & 1u));
  return h;
}

// ---- prepass: pack f16 weights, per-(wave,lane)-contiguous ----
// All three 256x64 matrices share one layout: lane l, dword d (0..127):
//   r = d>>5 (gate), kp = d&31, row = r*64+l, cols (2kp, 2kp+1).
// region A [    0, 8192): Whh0  (wave0)
// region B [ 8192,16384): Whh1  (wave2)
// region C [16384,24576): Wih1  (wave1)
// region E [24576,25088): head: lane l (m=l>>2,kq=l&3), d=0..7:
//   Wlin[m][kq*16+2d], +1
__global__ void pack_w(const float* __restrict__ Whh0,
                       const float* __restrict__ Whh1,
                       const float* __restrict__ Wih1,
                       const float* __restrict__ Wlin,
                       unsigned* __restrict__ ws) {
  int i = blockIdx.x * 256 + threadIdx.x;
  if (i >= 25088) return;
  float v0, v1;
  if (i < 24576) {
    int w = i >> 13, rem = i & 8191, l = rem >> 7, d = rem & 127;
    int r = d >> 5, kp = d & 31, row = r * 64 + l;
    const float* src = (w == 0) ? Whh0 : (w == 1) ? Whh1 : Wih1;
    v0 = src[row * 64 + 2 * kp]; v1 = src[row * 64 + 2 * kp + 1];
  } else {
    int j = i - 24576, l = j >> 3, d = j & 7;
    int m = l >> 2, kq = l & 3, k = kq * 16 + 2 * d;
    v0 = Wlin[m * 64 + k]; v1 = Wlin[m * 64 + k + 1];
  }
  ws[i] = f16rne(v0) | (f16rne(v1) << 16);
}

#define DECLW32(wp)                                                            \
  u4 W0=(wp)[0],  W1=(wp)[1],  W2=(wp)[2],  W3=(wp)[3],                        \
     W4=(wp)[4],  W5=(wp)[5],  W6=(wp)[6],  W7=(wp)[7],                        \
     W8=(wp)[8],  W9=(wp)[9],  W10=(wp)[10],W11=(wp)[11],                      \
     W12=(wp)[12],W13=(wp)[13],W14=(wp)[14],W15=(wp)[15],                      \
     W16=(wp)[16],W17=(wp)[17],W18=(wp)[18],W19=(wp)[19],                      \
     W20=(wp)[20],W21=(wp)[21],W22=(wp)[22],W23=(wp)[23],                      \
     W24=(wp)[24],W25=(wp)[25],W26=(wp)[26],W27=(wp)[27],                      \
     W28=(wp)[28],W29=(wp)[29],W30=(wp)[30],W31=(wp)[31]

#define PINW8(a,b,c,d,e,f,g,h)                                                 \
  asm volatile("" : "+v"(a), "+v"(b), "+v"(c), "+v"(d),                        \
                    "+v"(e), "+v"(f), "+v"(g), "+v"(h))
#define PINALL() { PINW8(W0,W1,W2,W3,W4,W5,W6,W7);                             \
                   PINW8(W8,W9,W10,W11,W12,W13,W14,W15);                       \
                   PINW8(W16,W17,W18,W19,W20,W21,W22,W23);                     \
                   PINW8(W24,W25,W26,W27,W28,W29,W30,W31); }

__global__ __launch_bounds__(192)
__attribute__((amdgpu_waves_per_eu(1, 1)))
void rnn_fused(
    const float* __restrict__ y,
    const float* __restrict__ Wih0, const float* __restrict__ bih0,
    const float* __restrict__ bhh0,
    const float* __restrict__ bih1, const float* __restrict__ bhh1,
    const float* __restrict__ blin,
    const unsigned* __restrict__ ws,
    float* __restrict__ out)
{
  const int tid = threadIdx.x;
  // rings: block j occupies slots [j*B .. j*B+B) & (RS-1) — adjacent blocks
  // land in disjoint halves, so producer/consumer never touch the same half
  // within one superstep.
  __shared__ __align__(16) unsigned h0r[RS * 32];   // h0 packed f16 pairs, 8 KB
  __shared__ __align__(16) unsigned h1r[RS * 32];   // h1 packed f16 pairs, 8 KB
  __shared__ __align__(16) float    xp[RS * 256];   // xp1 f32 (gate-major), 64 KB

  for (int j = tid; j < RS * 32; j += 192) { h0r[j] = 0u; h1r[j] = 0u; }
  __syncthreads();

  if (tid < 64) {
    // ================= wave0: layer 0, all 4 gates per lane =================
    const int e = tid;
    const u4* wp = (const u4*)(ws + e * 128);
    DECLW32(wp);
    float bbi = bih0[e] + bhh0[e];
    float bbf = bih0[64 + e] + bhh0[64 + e];
    float bbg = bih0[128 + e] + bhh0[128 + e];
    float bbo = bih0[192 + e] + bhh0[192 + e];
    float wii = Wih0[e], wif = Wih0[64 + e], wig = Wih0[128 + e], wio = Wih0[192 + e];
    float c0 = 0.f;
    float ylv = y[e & (B - 1)];                       // lanes 0..31 hold y[0..31]

    for (int k = 0; k < K_SS; ++k) {
      if (k < NB) {
        float yln = (k + 1 < NB) ? y[(k + 1) * B + (e & (B - 1))] : 0.f;
        const int base = k * B;
        #pragma unroll 1
        for (int i = 0; i < B; ++i) {
          const int s = base + i;
          PINALL();
          const u4* hp = (const u4*)(h0r + ((s - 1) & (RS - 1)) * 32);
          u4 H0=hp[0],H1=hp[1],H2=hp[2],H3=hp[3],H4=hp[4],H5=hp[5],H6=hp[6],H7=hp[7];
          float ys = __builtin_bit_cast(float,
              __builtin_amdgcn_readlane(__builtin_bit_cast(int, ylv), i));
          float ai0=0,ai1=0, af0=0,af1=0, ag0=0,ag1=0, ao0=0,ao1=0;
          DP4(ai0,W0,H0)  DP4(af0,W8,H0)  DP4(ag0,W16,H0) DP4(ao0,W24,H0)
          DP4(ai1,W1,H1)  DP4(af1,W9,H1)  DP4(ag1,W17,H1) DP4(ao1,W25,H1)
          DP4(ai0,W2,H2)  DP4(af0,W10,H2) DP4(ag0,W18,H2) DP4(ao0,W26,H2)
          DP4(ai1,W3,H3)  DP4(af1,W11,H3) DP4(ag1,W19,H3) DP4(ao1,W27,H3)
          DP4(ai0,W4,H4)  DP4(af0,W12,H4) DP4(ag0,W20,H4) DP4(ao0,W28,H4)
          DP4(ai1,W5,H5)  DP4(af1,W13,H5) DP4(ag1,W21,H5) DP4(ao1,W29,H5)
          DP4(ai0,W6,H6)  DP4(af0,W14,H6) DP4(ag0,W22,H6) DP4(ao0,W30,H6)
          DP4(ai1,W7,H7)  DP4(af1,W15,H7) DP4(ag1,W23,H7) DP4(ao1,W31,H7)
          float I = sigf((ai0 + ai1) + fmaf(ys, wii, bbi));
          float F = sigf((af0 + af1) + fmaf(ys, wif, bbf));
          float G = tanhf_((ag0 + ag1) + fmaf(ys, wig, bbg));
          float O = sigf((ao0 + ao1) + fmaf(ys, wio, bbo));
          c0 = fmaf(F, c0, I * G);
          float h = O * tanhf_(c0);
          float hp1 = DPPX1(h);
          unsigned pk = __builtin_bit_cast(unsigned, __builtin_amdgcn_cvt_pkrtz(h, hp1));
          if (!(e & 1)) h0r[(s & (RS - 1)) * 32 + (e >> 1)] = pk;
        }
        ylv = yln;
      }
      BARRIER();
    }
  } else if (tid < 128) {
    // ========= wave1: xp1 producer (block k-1) + head (block k-3) =========
    const int e = tid - 64;
    const u4* wp = (const u4*)(ws + 16384 + e * 128);
    DECLW32(wp);
    const u4* hwp = (const u4*)(ws + 24576 + e * 8);
    u4 HW0 = hwp[0], HW1 = hwp[1];
    float bb0 = bih1[e] + bhh1[e];
    float bb1 = bih1[64 + e] + bhh1[64 + e];
    float bb2 = bih1[128 + e] + bhh1[128 + e];
    float bb3 = bih1[192 + e] + bhh1[192 + e];
    const int m = e >> 2, kq = e & 3;
    float bl = (kq == 0) ? blin[m] : 0.f;

    for (int k = 0; k < K_SS; ++k) {
      if (k >= 1 && k <= NB) {                         // xp1 for block k-1
        const int base = (k - 1) * B;
        #pragma unroll 1
        for (int i = 0; i < B; ++i) {
          const int t = base + i;
          const int slot = t & (RS - 1);
          PINALL();
          const u4* hp = (const u4*)(h0r + slot * 32);
          u4 H0=hp[0],H1=hp[1],H2=hp[2],H3=hp[3],H4=hp[4],H5=hp[5],H6=hp[6],H7=hp[7];
          float p0a=0,p0b=0, p1a=0,p1b=0, p2a=0,p2b=0, p3a=0,p3b=0;
          DP4(p0a,W0,H0) DP4(p1a,W8,H0)  DP4(p2a,W16,H0) DP4(p3a,W24,H0)
          DP4(p0b,W1,H1) DP4(p1b,W9,H1)  DP4(p2b,W17,H1) DP4(p3b,W25,H1)
          DP4(p0a,W2,H2) DP4(p1a,W10,H2) DP4(p2a,W18,H2) DP4(p3a,W26,H2)
          DP4(p0b,W3,H3) DP4(p1b,W11,H3) DP4(p2b,W19,H3) DP4(p3b,W27,H3)
          DP4(p0a,W4,H4) DP4(p1a,W12,H4) DP4(p2a,W20,H4) DP4(p3a,W28,H4)
          DP4(p0b,W5,H5) DP4(p1b,W13,H5) DP4(p2b,W21,H5) DP4(p3b,W29,H5)
          DP4(p0a,W6,H6) DP4(p1a,W14,H6) DP4(p2a,W22,H6) DP4(p3a,W30,H6)
          DP4(p0b,W7,H7) DP4(p1b,W15,H7) DP4(p2b,W23,H7) DP4(p3b,W31,H7)
          float* xq = xp + slot * 256;
          xq[e]       = (p0a + p0b) + bb0;
          xq[64 + e]  = (p1a + p1b) + bb1;
          xq[128 + e] = (p2a + p2b) + bb2;
          xq[192 + e] = (p3a + p3b) + bb3;
        }
      }
      if (k >= 3) {                                    // head for block k-3
        const int base = (k - 3) * B;
        #pragma unroll 1
        for (int i = 0; i < B; ++i) {
          const int t = base + i;
          const int slot = t & (RS - 1);
          const u4* h1p = (const u4*)(h1r + slot * 32 + kq * 8);
          u4 X0 = h1p[0], X1 = h1p[1];
          float r2 = 0.f;
          DP4(r2, HW0, X0) DP4(r2, HW1, X1)
          r2 += DPPX1(r2);
          r2 += DPPX2(r2);                             // sum over kq (quad)
          if (kq == 0) out[t * 16 + m] = r2 + bl;
        }
      }
      BARRIER();
    }
  } else {
    // ============ wave2: layer-1 recurrence (block k-2), in-lane ============
    const int e = tid - 128;
    const u4* wp = (const u4*)(ws + 8192 + e * 128);
    DECLW32(wp);
    float c1 = 0.f;

    for (int k = 0; k < K_SS; ++k) {
      if (k >= 2 && k <= NB + 1) {
        const int base = (k - 2) * B;
        #pragma unroll 1
        for (int i = 0; i < B; ++i) {
          const int t = base + i;
          const int slot = t & (RS - 1);
          PINALL();
          const u4* hp = (const u4*)(h1r + ((t - 1) & (RS - 1)) * 32);
          u4 H0=hp[0],H1=hp[1],H2=hp[2],H3=hp[3],H4=hp[4],H5=hp[5],H6=hp[6],H7=hp[7];
          float ai0=0,ai1=0, af0=0,af1=0, ag0=0,ag1=0, ao0=0,ao1=0;
          DP4(ai0,W0,H0)  DP4(af0,W8,H0)  DP4(ag0,W16,H0) DP4(ao0,W24,H0)
          DP4(ai1,W1,H1)  DP4(af1,W9,H1)  DP4(ag1,W17,H1) DP4(ao1,W25,H1)
          DP4(ai0,W2,H2)  DP4(af0,W10,H2) DP4(ag0,W18,H2) DP4(ao0,W26,H2)
          DP4(ai1,W3,H3)  DP4(af1,W11,H3) DP4(ag1,W19,H3) DP4(ao1,W27,H3)
          DP4(ai0,W4,H4)  DP4(af0,W12,H4) DP4(ag0,W20,H4) DP4(ao0,W28,H4)
          DP4(ai1,W5,H5)  DP4(af1,W13,H5) DP4(ag1,W21,H5) DP4(ao1,W29,H5)
          DP4(ai0,W6,H6)  DP4(af0,W14,H6) DP4(ag0,W22,H6) DP4(ao0,W30,H6)
          DP4(ai1,W7,H7)  DP4(af1,W15,H7) DP4(ag1,W23,H7) DP4(ao1,W31,H7)
          const float* xq = xp + slot * 256;
          float xi = xq[e], xf = xq[64 + e], xg = xq[128 + e], xo = xq[192 + e];
          float I = sigf(xi + (ai0 + ai1));
          float F = sigf(xf + (af0 + af1));
          float G = tanhf_(xg + (ag0 + ag1));
          float O = sigf(xo + (ao0 + ao1));
          c1 = fmaf(F, c1, I * G);
          float h = O * tanhf_(c1);
          float hp1 = DPPX1(h);
          unsigned pk = __builtin_bit_cast(unsigned, __builtin_amdgcn_cvt_pkrtz(h, hp1));
          if (!(e & 1)) h1r[slot * 32 + (e >> 1)] = pk;
        }
      }
      BARRIER();
    }
  }
}

extern "C" void kernel_launch(void* const* d_in, const int* in_sizes, int n_in,
                              void* d_out, int out_size, void* d_ws, size_t ws_size,
                              hipStream_t stream) {
  const float* y    = (const float*)d_in[0];
  const float* Wih0 = (const float*)d_in[1];
  const float* Whh0 = (const float*)d_in[2];
  const float* bih0 = (const float*)d_in[3];
  const float* bhh0 = (const float*)d_in[4];
  const float* Wih1 = (const float*)d_in[5];
  const float* Whh1 = (const float*)d_in[6];
  const float* bih1 = (const float*)d_in[7];
  const float* bhh1 = (const float*)d_in[8];
  const float* Wlin = (const float*)d_in[9];
  const float* blin = (const float*)d_in[10];
  unsigned* ws = (unsigned*)d_ws;                // 25088 dwords ~= 100 KB

  pack_w<<<dim3(98), dim3(256), 0, stream>>>(Whh0, Whh1, Wih1, Wlin, ws);
  rnn_fused<<<dim3(1), dim3(192), 0, stream>>>(
      y, Wih0, bih0, bhh0, bih1, bhh1, blin, ws, (float*)d_out);
}